// Round 1
// baseline (1295.084 us; speedup 1.0000x reference)
//
#include <hip/hip_runtime.h>

// ScaledDotProductAttention: B=4,H=8,L=2048,DK=DV=32
// out = [context (B,H,L,DV) | scores (B,H,L,L)] f32, concatenated.
// Flash-style single pass; one block = 64 query rows of one (b,h); 4 waves.
// KEY CHANGE vs prev (1648us): compute S^T = mfma(K, Q) so each lane owns
// ONE query row and 4-consecutive key columns -> res/mask/scores become
// dwordx4 streams (were scalar dword: 48 VMEM/thread/iter -> 12), softmax
// reduction 2 shuffles (was 16), P staging b64 writes (was scalar b16),
// ctx epilogue float4. PV computes O^T = mfma(V^T, P^T): identical LDS
// layouts/reads as before, only operand order swaps.
// res/mask loads hoisted before staging barrier (latency hides under K/V
// stage); res/mask/scores use nontemporal (single-use streams; keep L2
// for K/V which 32 blocks share per (b,h)).

#define NB 4
#define NH 8
#define SL 2048
#define DKx 32
#define DVx 32
#define BM 64
#define BN 64
#define SCALE 0.17677669529663687f

typedef __bf16 bf16x8 __attribute__((ext_vector_type(8)));
typedef float f32x4 __attribute__((ext_vector_type(4)));
typedef short s16x4 __attribute__((ext_vector_type(4)));
typedef int   i32x4 __attribute__((ext_vector_type(4)));

union BF8 { short s[8]; bf16x8 v; };

__device__ __forceinline__ short f2bf(float x) {
  union { float f; unsigned u; } c; c.f = x;
  unsigned r = c.u + 0x7FFFu + ((c.u >> 16) & 1u);
  return (short)(r >> 16);
}
__device__ __forceinline__ float bf2f(short h) {
  union { float f; unsigned u; } c; c.u = ((unsigned)(unsigned short)h) << 16;
  return c.f;
}

__global__ __launch_bounds__(256, 4)
void fa_kernel(const float* __restrict__ Q, const float* __restrict__ K,
               const float* __restrict__ V, const int* __restrict__ mask,
               const float* __restrict__ res, float* __restrict__ ctx,
               float* __restrict__ scores)
{
  // Padded LDS: +8 shorts per row -> 16B-aligned b128 reads, <=2-way bank conflicts.
  __shared__ short Khi[BN][40], Klo[BN][40];      // [key][k]
  __shared__ short Vhi[DVx][72], Vlo[DVx][72];    // [v][key] (A-frag for O^T)
  __shared__ short Phi[4][16][72], Plo[4][16][72];// per-wave [query][key]

  const int tid  = threadIdx.x;
  const int w    = tid >> 6;
  const int lane = tid & 63;
  const int q    = lane >> 4;    // quad
  const int t16  = lane & 15;
  const int bh = blockIdx.y, qt = blockIdx.x;

  // Q fragment (split hi/lo) used as MFMA *B* operand: B[k=dk][n=query]
  // lane holds n = t16 (query), k = q*8+j (dk). Same data as old A-frag.
  const float* qp = Q + ((size_t)bh * SL + qt * BM + w * 16 + t16) * DKx + q * 8;
  BF8 qhi, qlo;
#pragma unroll
  for (int j = 0; j < 8; ++j) {
    float x = qp[j];
    short h = f2bf(x);
    qhi.s[j] = h;
    qlo.s[j] = f2bf(x - bf2f(h));
  }

  // O^T accumulator: accO[nc][i] = O[v = nc*16 + q*4 + i][query = t16-row]
  f32x4 accO[2];
  accO[0] = (f32x4)(0.f); accO[1] = (f32x4)(0.f);
  float m_i = -INFINITY;   // one query row per lane now
  float l_i = 0.f;

  // This lane's single query row (flattened over b,h)
  const size_t qrow = (size_t)bh * SL + qt * BM + w * 16 + t16;
  const float* resp = res    + qrow * SL + q * 4;
  const int*   mskp = mask   + qrow * SL + q * 4;
  float*       scp  = scores + qrow * SL + q * 4;

  for (int kt = 0; kt < SL / BN; ++kt) {
    const int off = kt * BN;

    // ---- hoisted streaming loads: latency hides under K/V staging ----
    f32x4 rv[4]; i32x4 mv[4];
#pragma unroll
    for (int c = 0; c < 4; ++c) {
      rv[c] = __builtin_nontemporal_load((const f32x4*)(resp + off + c * 16));
      mv[c] = __builtin_nontemporal_load((const i32x4*)(mskp + off + c * 16));
    }

    __syncthreads();  // protect K/V LDS from previous iteration's readers

    // ---- stage K (split bf16) and V (transposed, split bf16) ----
#pragma unroll
    for (int it = 0; it < 2; ++it) {
      int e  = tid + it * 256;        // 0..511
      int n  = e >> 3;                // key row 0..63
      int c4 = (e & 7) * 4;           // element quad 0..28
      const float4 kv = *(const float4*)(K + ((size_t)bh * SL + off + n) * DKx + c4);
      float ka[4] = { kv.x, kv.y, kv.z, kv.w };
      s16x4 hh, ll;
#pragma unroll
      for (int j = 0; j < 4; ++j) {
        short h = f2bf(ka[j]);
        hh[j] = h;
        ll[j] = f2bf(ka[j] - bf2f(h));
      }
      *(s16x4*)&Khi[n][c4] = hh;
      *(s16x4*)&Klo[n][c4] = ll;

      const float4 vv = *(const float4*)(V + ((size_t)bh * SL + off + n) * DVx + c4);
      float va[4] = { vv.x, vv.y, vv.z, vv.w };
#pragma unroll
      for (int j = 0; j < 4; ++j) {
        short h = f2bf(va[j]);
        Vhi[c4 + j][n] = h;
        Vlo[c4 + j][n] = f2bf(va[j] - bf2f(h));
      }
    }
    __syncthreads();

    // ---- S^T = K Q^T (split-bf16, 3 MFMA terms per 16x16 tile) ----
    // accs[c][i] = S[key = off + c*16 + q*4 + i][query = qrow]
    f32x4 accs[4];
#pragma unroll
    for (int c = 0; c < 4; ++c) accs[c] = (f32x4)(0.f);
#pragma unroll
    for (int c = 0; c < 4; ++c) {
      bf16x8 kh = *(const bf16x8*)&Khi[c * 16 + t16][q * 8];
      bf16x8 kl = *(const bf16x8*)&Klo[c * 16 + t16][q * 8];
      accs[c] = __builtin_amdgcn_mfma_f32_16x16x32_bf16(kh, qhi.v, accs[c], 0, 0, 0);
      accs[c] = __builtin_amdgcn_mfma_f32_16x16x32_bf16(kh, qlo.v, accs[c], 0, 0, 0);
      accs[c] = __builtin_amdgcn_mfma_f32_16x16x32_bf16(kl, qhi.v, accs[c], 0, 0, 0);
    }

    // ---- scale + res + mask; vectorized score stream-out ----
    f32x4 sv[4];
#pragma unroll
    for (int c = 0; c < 4; ++c) {
#pragma unroll
      for (int i = 0; i < 4; ++i) {
        float s = accs[c][i] * SCALE + rv[c][i];
        sv[c][i] = mv[c][i] ? -1.0e9f : s;
      }
      __builtin_nontemporal_store(sv[c], (f32x4*)(scp + off + c * 16));
    }

    // ---- online softmax: lane owns one query row; 16 in-lane keys,
    //      quads exchanged via xor 16/32 ----
    float tm = sv[0][0];
#pragma unroll
    for (int c = 0; c < 4; ++c)
#pragma unroll
      for (int i = 0; i < 4; ++i) tm = fmaxf(tm, sv[c][i]);
    tm = fmaxf(tm, __shfl_xor(tm, 16));
    tm = fmaxf(tm, __shfl_xor(tm, 32));
    float mn = fmaxf(m_i, tm);
    float a  = __expf(m_i - mn);
    m_i = mn;

    float p[4][4];
    float rs = 0.f;
#pragma unroll
    for (int c = 0; c < 4; ++c)
#pragma unroll
      for (int i = 0; i < 4; ++i) {
        float e_ = __expf(sv[c][i] - mn);
        p[c][i] = e_;
        rs += e_;
      }
    rs += __shfl_xor(rs, 16);
    rs += __shfl_xor(rs, 32);
    l_i = l_i * a + rs;
    accO[0] *= a;
    accO[1] *= a;

    // ---- P^T -> LDS [query][key] (split bf16, vector b64 writes) ----
#pragma unroll
    for (int c = 0; c < 4; ++c) {
      s16x4 hh, ll;
#pragma unroll
      for (int i = 0; i < 4; ++i) {
        short h = f2bf(p[c][i]);
        hh[i] = h;
        ll[i] = f2bf(p[c][i] - bf2f(h));
      }
      *(s16x4*)&Phi[w][t16][c * 16 + q * 4] = hh;
      *(s16x4*)&Plo[w][t16][c * 16 + q * 4] = ll;
    }
    // (same-wave LDS write->read: lgkmcnt ordering, no barrier needed)

    // ---- O^T += V^T P^T (split-bf16, 3 terms) ----
#pragma unroll
    for (int kc = 0; kc < 2; ++kc) {
      bf16x8 ph = *(const bf16x8*)&Phi[w][t16][kc * 32 + q * 8];
      bf16x8 pl = *(const bf16x8*)&Plo[w][t16][kc * 32 + q * 8];
#pragma unroll
      for (int nc = 0; nc < 2; ++nc) {
        bf16x8 vh = *(const bf16x8*)&Vhi[nc * 16 + t16][kc * 32 + q * 8];
        bf16x8 vl = *(const bf16x8*)&Vlo[nc * 16 + t16][kc * 32 + q * 8];
        accO[nc] = __builtin_amdgcn_mfma_f32_16x16x32_bf16(vh, ph, accO[nc], 0, 0, 0);
        accO[nc] = __builtin_amdgcn_mfma_f32_16x16x32_bf16(vl, ph, accO[nc], 0, 0, 0);
        accO[nc] = __builtin_amdgcn_mfma_f32_16x16x32_bf16(vh, pl, accO[nc], 0, 0, 0);
      }
    }
  }

  // ---- epilogue: context = O / l (vectorized float4 stores) ----
  const float inv_l = 1.f / l_i;
#pragma unroll
  for (int nc = 0; nc < 2; ++nc) {
    f32x4 o;
#pragma unroll
    for (int i = 0; i < 4; ++i) o[i] = accO[nc][i] * inv_l;
    *(f32x4*)(ctx + qrow * DVx + nc * 16 + q * 4) = o;
  }
}

extern "C" void kernel_launch(void* const* d_in, const int* in_sizes, int n_in,
                              void* d_out, int out_size, void* d_ws, size_t ws_size,
                              hipStream_t stream) {
  const float* Q    = (const float*)d_in[0];
  const float* K    = (const float*)d_in[1];
  const float* V    = (const float*)d_in[2];
  const int*   mask = (const int*)d_in[3];   // bool mask, int32 on device
  const float* res  = (const float*)d_in[4];
  float* ctx    = (float*)d_out;
  float* scores = (float*)d_out + (size_t)NB * NH * SL * DVx;

  dim3 grid(SL / BM, NB * NH);
  fa_kernel<<<grid, dim3(256), 0, stream>>>(Q, K, V, mask, res, ctx, scores);
}